// Round 12
// baseline (393.735 us; speedup 1.0000x reference)
//
#include <hip/hip_runtime.h>
#include <hip/hip_bf16.h>
#include <hip/hip_fp16.h>
#include <math.h>

#define NB 64
#define CC 512
#define LL 256

typedef __attribute__((ext_vector_type(4))) float floatx4;
typedef __attribute__((ext_vector_type(8))) short short8;

static __device__ __forceinline__ unsigned f2bf2(float x, float y) {
    __hip_bfloat162 h = __float22bfloat162_rn(make_float2(x, y));
    union { __hip_bfloat162 h; unsigned u; } c; c.h = h;
    return c.u;   // low 16 = x, high 16 = y
}
static __device__ __forceinline__ unsigned short f2h(float x) {
    __half h = __float2half_rn(x);
    union { __half h; unsigned short u; } c; c.h = h;
    return c.u;
}
static __device__ __forceinline__ float h2f(unsigned u) {
    union { unsigned short u; __half h; } c; c.u = (unsigned short)u;
    return __half2float(c.h);
}

// ---------------- K0: ballot compaction -> idx/npos, zero sums/counters/out ----------
__global__ __launch_bounds__(256) void prep_kernel(
    const int* __restrict__ targets,
    int* __restrict__ idx, int* __restrict__ npos,
    float* __restrict__ sumS, float* __restrict__ sumT,
    int* __restrict__ count, float* __restrict__ out)
{
    const int n = blockIdx.x, tid = threadIdx.x;
    __shared__ int s_cnt[8], s_off[8];
    const int w = tid >> 6, lane = tid & 63;
    const int* tg = targets + n * CC;
    const bool p0 = tg[tid] != 0;
    const bool p1 = tg[tid + 256] != 0;
    const unsigned long long m0 = __ballot(p0);
    const unsigned long long m1 = __ballot(p1);
    if (lane == 0) { s_cnt[w] = __popcll(m0); s_cnt[4 + w] = __popcll(m1); }
    __syncthreads();
    if (tid == 0) {
        int a = 0;
        for (int i = 0; i < 8; ++i) { s_off[i] = a; a += s_cnt[i]; }
        npos[n] = a;
        sumS[n] = 0.0f; sumT[n] = 0.0f;
        count[n * 16] = 0;
        if (n == 0) out[0] = 0.0f;
    }
    __syncthreads();
    const unsigned long long below = (1ull << lane) - 1ull;
    if (p0) idx[n * CC + s_off[w] + __popcll(m0 & below)] = tid;
    if (p1) idx[n * CC + s_off[4 + w] + __popcll(m1 & below)] = tid + 256;
}

// decode linear t -> upper-tri (tI,tJ) of a u x u tile grid
static __device__ __forceinline__ bool decode_tile(int t, int u, int& tI, int& tJ) {
    if (t >= (u * (u + 1)) >> 1) return false;
    tI = 0;
    while (t >= u - tI) { t -= u - tI; ++tI; }
    tJ = tI + t;
    return true;
}

// ---------------- K1: single-matrix Gram+distances, tail block does batch Huber ------
// bx = (t*2+mat)*64 + n  =>  bx % 8 == n % 8 (XCD-clustered per batch).
// 2-deep staging prefetch; dbuf LDS, 1 barrier/chunk. After its tile, each active
// block bumps count[n]; the unique last arrival (no waiting!) computes the batch's
// Huber sum over all stored D tiles (L2-hot on this XCD) and adds to out.
__global__ __launch_bounds__(256) void dist_kernel(
    const float* __restrict__ S, const float* __restrict__ T,
    const int* __restrict__ idx, const int* __restrict__ npos,
    float* __restrict__ sumS, float* __restrict__ sumT,
    int* __restrict__ count,
    unsigned short* __restrict__ Ds, unsigned short* __restrict__ Dt,
    float* __restrict__ out)
{
    const int bx = blockIdx.x;
    const int n = bx & (NB - 1);
    const int q = bx >> 6;
    const int mat = q & 1, t = q >> 1;
    const int np = npos[n];
    if (np < 2) return;
    const int u = (np + 63) >> 6;
    const int ntiles = (u * (u + 1)) >> 1;
    int tI, tJ;
    if (!decode_tile(t, u, tI, tJ)) return;
    const bool diag = (tI == tJ);

    __shared__ __align__(16) unsigned short lds[2][2][64][40];   // 20.5 KB
    __shared__ float s_norm[2][64];
    __shared__ float red[4];
    __shared__ int s_tail;

    const int tid = threadIdx.x;
    const int w = tid >> 6, lane = tid & 63;

    const float* P = (mat ? T : S) + (size_t)n * CC * LL;
    unsigned short* Dout = (mat ? Dt : Ds) + (((size_t)t * NB + n) << 12);
    float* sumP = mat ? sumT : sumS;

    // staging: logical rows 0..127 = A rows then B rows (diag: A only); 2 lanes/row
    const int srow = w * 32 + (lane >> 1);
    const int half = lane & 1;
    const bool stager = diag ? (srow < 64) : true;
    const int ab = srow >> 6, rloc = srow & 63;
    const int gk = (ab ? tJ : tI) * 64 + rloc;
    const int row = idx[n * CC + ((gk < np) ? gk : 0)];
    const char* rp = (const char*)P + (size_t)row * (LL * 4) + half * 64;

    float4 pre[2][4];
    float nsum = 0.0f;
    if (stager) {
        #pragma unroll
        for (int i = 0; i < 4; ++i) pre[0][i] = *(const float4*)(rp + i * 16);
        #pragma unroll
        for (int i = 0; i < 4; ++i) pre[1][i] = *(const float4*)(rp + 128 + i * 16);
    }

    const int m16 = lane & 15, quad = lane >> 4;
    const int bufB = diag ? 0 : 1;
    const int wrow = w * 16;

    floatx4 acc[4];
    #pragma unroll
    for (int c = 0; c < 4; ++c) { acc[c][0] = 0; acc[c][1] = 0; acc[c][2] = 0; acc[c][3] = 0; }

    for (int kk = 0; kk < 8; ++kk) {
        const int pb = kk & 1;
        if (stager) {
            #pragma unroll
            for (int i = 0; i < 4; ++i)
                nsum += pre[pb][i].x * pre[pb][i].x + pre[pb][i].y * pre[pb][i].y +
                        pre[pb][i].z * pre[pb][i].z + pre[pb][i].w * pre[pb][i].w;
            unsigned short* dst = &lds[ab][pb][rloc][half * 16];
            *(uint2*)(dst + 0)  = make_uint2(f2bf2(pre[pb][0].x, pre[pb][0].y), f2bf2(pre[pb][0].z, pre[pb][0].w));
            *(uint2*)(dst + 4)  = make_uint2(f2bf2(pre[pb][1].x, pre[pb][1].y), f2bf2(pre[pb][1].z, pre[pb][1].w));
            *(uint2*)(dst + 8)  = make_uint2(f2bf2(pre[pb][2].x, pre[pb][2].y), f2bf2(pre[pb][2].z, pre[pb][2].w));
            *(uint2*)(dst + 12) = make_uint2(f2bf2(pre[pb][3].x, pre[pb][3].y), f2bf2(pre[pb][3].z, pre[pb][3].w));
        }
        __syncthreads();   // single barrier per chunk
        if (stager && kk < 6) {                // refill freed buffer with chunk kk+2
            #pragma unroll
            for (int i = 0; i < 4; ++i)
                pre[pb][i] = *(const float4*)(rp + (kk + 2) * 128 + i * 16);
        }
        const short8 a = *(const short8*)&lds[0][pb][wrow + m16][quad * 8];
        #pragma unroll
        for (int c = 0; c < 4; ++c) {
            const short8 b = *(const short8*)&lds[bufB][pb][c * 16 + m16][quad * 8];
            acc[c] = __builtin_amdgcn_mfma_f32_16x16x32_bf16(a, b, acc[c], 0, 0, 0);
        }
    }

    // ---- inline norms: 2 lanes share each staged row ----
    if (stager) {
        const float v = nsum + __shfl_xor(nsum, 1);
        if (half == 0) s_norm[ab][rloc] = v;
    }
    __syncthreads();

    // ---- distances; C/D layout: col=lane&15, row=quad*4+reg ----
    float l0 = 0.0f;
    #pragma unroll
    for (int c = 0; c < 4; ++c) {
        const int colL = c * 16 + m16;
        const int gj = tJ * 64 + colL;
        const float nB = s_norm[bufB][colL];
        #pragma unroll
        for (int r = 0; r < 4; ++r) {
            const int rowL = wrow + quad * 4 + r;
            const int gi = tI * 64 + rowL;
            const float d = sqrtf(fmaxf(s_norm[0][rowL] + nB - 2.0f * acc[c][r], 1e-12f));
            if (gi < np && gj < np && gi != gj) l0 += d;
            Dout[rowL * 64 + colL] = f2h(d);
        }
    }

    #pragma unroll
    for (int o = 32; o; o >>= 1) l0 += __shfl_down(l0, o);
    if (lane == 0) red[w] = l0;
    __syncthreads();

    // ---- arrival: unique last block of batch n does the Huber (no waiting) ----
    __threadfence();                            // all threads: D writes device-visible
    __syncthreads();
    if (tid == 0) {
        const float wgt = diag ? 1.0f : 2.0f;
        atomicAdd(sumP + n, wgt * (red[0] + red[1] + red[2] + red[3]));
        __threadfence();
        const int old = __hip_atomic_fetch_add(&count[n * 16], 1, __ATOMIC_ACQ_REL,
                                               __HIP_MEMORY_SCOPE_AGENT);
        s_tail = (old == 2 * ntiles - 1);
    }
    __syncthreads();
    if (!s_tail) return;
    __threadfence();                            // acquire side: invalidate caches

    const float cp = (float)np * (float)(np - 1);
    const float inv_ms = cp / __hip_atomic_load(&sumS[n], __ATOMIC_RELAXED,
                                                __HIP_MEMORY_SCOPE_AGENT);
    const float inv_mt = cp / __hip_atomic_load(&sumT[n], __ATOMIC_RELAXED,
                                                __HIP_MEMORY_SCOPE_AGENT);

    float h = 0.0f;
    int ti = 0, tj = 0;
    for (int tt = 0; tt < ntiles; ++tt) {
        const size_t slot = ((size_t)tt * NB + n) << 12;
        const uint4* ps = (const uint4*)(Ds + slot);   // 512 uint4 per tile
        const uint4* pt = (const uint4*)(Dt + slot);
        const float wgt = (ti == tj) ? 1.0f : 2.0f;
        float hp = 0.0f;
        #pragma unroll
        for (int it = 0; it < 2; ++it) {
            const int g = it * 256 + tid;
            const uint4 a = ps[g];
            const uint4 b = pt[g];
            const unsigned aw[4] = { a.x, a.y, a.z, a.w };
            const unsigned bw[4] = { b.x, b.y, b.z, b.w };
            const int e0 = g * 8;
            #pragma unroll
            for (int k = 0; k < 8; ++k) {
                const int e = e0 + k;
                const int gi = ti * 64 + (e >> 6);
                const int gj = tj * 64 + (e & 63);
                if (gi < np && gj < np && gi != gj) {
                    const unsigned wa = aw[k >> 1], wb = bw[k >> 1];
                    const float ds = h2f((k & 1) ? (wa >> 16) : (wa & 0xffffu));
                    const float dt = h2f((k & 1) ? (wb >> 16) : (wb & 0xffffu));
                    const float diff = ds * inv_ms - dt * inv_mt;
                    const float ad = fabsf(diff);
                    hp += (ad < 1.0f) ? 0.5f * diff * diff : ad - 0.5f;
                }
            }
        }
        h += wgt * hp;
        ++tj;
        if (tj == u) { ++ti; tj = ti; }
    }

    #pragma unroll
    for (int o = 32; o; o >>= 1) h += __shfl_down(h, o);
    if (lane == 0) red[w] = h;
    __syncthreads();
    if (tid == 0)
        atomicAdd(out, (red[0] + red[1] + red[2] + red[3]) / (float)np);
}

extern "C" void kernel_launch(void* const* d_in, const int* in_sizes, int n_in,
                              void* d_out, int out_size, void* d_ws, size_t ws_size,
                              hipStream_t stream) {
    const float* S = (const float*)d_in[0];
    const float* T = (const float*)d_in[1];
    const int* targets = (const int*)d_in[2];
    float* out = (float*)d_out;

    char* p = (char*)d_ws;
    int* idx = (int*)p;        p += (size_t)NB * CC * 4;
    int* npos = (int*)p;       p += NB * 4;
    float* sumS = (float*)p;   p += NB * 4;
    float* sumT = (float*)p;   p += NB * 4;
    int* count = (int*)p;      p += NB * 16 * 4;   // 64 B-spaced counters
    p = (char*)(((size_t)p + 255) & ~(size_t)255);
    unsigned short* Ds = (unsigned short*)p;   p += (size_t)36 * NB * 4096 * 2;  // 18.9 MB
    unsigned short* Dt = (unsigned short*)p;                                      // 18.9 MB

    prep_kernel<<<NB, 256, 0, stream>>>(targets, idx, npos, sumS, sumT, count, out);
    dist_kernel<<<72 * NB, 256, 0, stream>>>(S, T, idx, npos, sumS, sumT, count,
                                             Ds, Dt, out);
}